// Round 1
// baseline (1501.749 us; speedup 1.0000x reference)
//
#include <hip/hip_runtime.h>
#include <math.h>

// ---------------- repack conv2 weights: w2[oc][ic][tap] -> w2p[ocg][ic][tap][16]
__global__ __launch_bounds__(256) void k_repack(const float* __restrict__ w2,
                                                float* __restrict__ w2p,
                                                float* __restrict__ lossAcc) {
  if (blockIdx.x == 0 && threadIdx.x == 0) lossAcc[0] = 0.f;
  int i = blockIdx.x * 256 + threadIdx.x;
  if (i < 18432) {
    int j = i & 15;
    int rest = i >> 4;        // (ocg*32+ic)*9 + tap
    int tap = rest % 9;
    int icc = rest / 9;
    int ic = icc & 31, ocg = icc >> 5;
    w2p[i] = w2[(ocg * 16 + j) * 288 + ic * 9 + tap];
  }
}

// ---------------- fused encoder: conv1 -> relu -> conv2 -> relu -> avgpool -> linear -> L2norm
__global__ __launch_bounds__(256) void k_encoder(
    const float* __restrict__ seq,
    const float* __restrict__ w1, const float* __restrict__ b1,
    const float* __restrict__ w2p, const float* __restrict__ b2,
    const float* __restrict__ lw, const float* __restrict__ lb,
    float* __restrict__ emb)
{
  __shared__ float s_in[32 * 33];
  __shared__ float s_w1[288];
  __shared__ float s_h1[4 * 32 * 64];   // [pr*2+pc][ic][ry*8+cx]
  __shared__ float s_pool[64];
  __shared__ float s_part[4];
  const int t = threadIdx.x;
  const float* x = seq + (size_t)blockIdx.x * 1024;
  for (int i = t; i < 1024; i += 256)
    s_in[(i >> 5) * 33 + (i & 31)] = x[i];
  for (int i = t; i < 288; i += 256) s_w1[i] = w1[i];
  __syncthreads();
  // conv1: 32x32 -> 32ch x 16x16 (stride2, SAME: pad lo 0, hi 1)
  {
    const int oy = t >> 4, ox = t & 15;
    float p[9];
#pragma unroll
    for (int dy = 0; dy < 3; ++dy)
#pragma unroll
      for (int dx = 0; dx < 3; ++dx) {
        const int iy = 2 * oy + dy, ix = 2 * ox + dx;
        p[dy * 3 + dx] = (iy < 32 && ix < 32) ? s_in[iy * 33 + ix] : 0.f;
      }
    const int base = ((oy & 1) * 2 + (ox & 1)) * 2048 + (oy >> 1) * 8 + (ox >> 1);
#pragma unroll
    for (int oc = 0; oc < 32; ++oc) {
      float a = b1[oc];
#pragma unroll
      for (int q = 0; q < 9; ++q) a = fmaf(p[q], s_w1[oc * 9 + q], a);
      s_h1[base + oc * 64] = fmaxf(a, 0.f);
    }
  }
  __syncthreads();
  // conv2: 32ch 16x16 -> 64ch 8x8 ; thread = (pos p, oc-group of 16)
  {
    const int p = t & 63, ocg = t >> 6;
    const int oy = p >> 3, ox = p & 7;
    float acc[16];
#pragma unroll
    for (int j = 0; j < 16; ++j) acc[j] = b2[ocg * 16 + j];
    for (int ic = 0; ic < 32; ++ic) {
      float q[9];
#pragma unroll
      for (int dy = 0; dy < 3; ++dy)
#pragma unroll
        for (int dx = 0; dx < 3; ++dx) {
          const int ry = oy + (dy >> 1), cx = ox + (dx >> 1);
          float v = 0.f;
          if (ry < 8 && cx < 8)
            v = s_h1[((dy & 1) * 2 + (dx & 1)) * 2048 + ic * 64 + ry * 8 + cx];
          q[dy * 3 + dx] = v;
        }
      const float* wp = w2p + (ocg * 32 + ic) * 144;
#pragma unroll
      for (int tap = 0; tap < 9; ++tap) {
        const float v = q[tap];
#pragma unroll
        for (int j = 0; j < 16; ++j)
          acc[j] = fmaf(v, wp[tap * 16 + j], acc[j]);
      }
    }
    // relu + avgpool over the 64 positions (= 64 lanes of this wave)
#pragma unroll
    for (int j = 0; j < 16; ++j) {
      float v = fmaxf(acc[j], 0.f);
#pragma unroll
      for (int off = 1; off < 64; off <<= 1) v += __shfl_xor(v, off, 64);
      if (p == 0) s_pool[ocg * 16 + j] = v * (1.f / 64.f);
    }
  }
  __syncthreads();
  // linear 64->128 + L2 normalize
  float val = 0.f;
  if (t < 128) {
    val = lb[t];
#pragma unroll 8
    for (int c = 0; c < 64; ++c) val = fmaf(s_pool[c], lw[c * 128 + t], val);
  }
  float sq = val * val;
#pragma unroll
  for (int off = 1; off < 64; off <<= 1) sq += __shfl_xor(sq, off, 64);
  if ((t & 63) == 0) s_part[t >> 6] = sq;
  __syncthreads();
  if (t < 128) {
    const float nrm = sqrtf(s_part[0] + s_part[1]);
    const float scale = 1.f / fmaxf(nrm, 1e-12f);
    emb[(size_t)blockIdx.x * 128 + t] = val * scale;
  }
}

// ---------------- A[b,t] = emb[b,t] @ emb[b,t+1]^T / tau  -> d_out+1
__global__ __launch_bounds__(256) void k_affinity(
    const float* __restrict__ emb, float* __restrict__ Aout)
{
  __shared__ float sAT[128 * 132];
  __shared__ float sBT[128 * 132];
  const int bid = blockIdx.x;
  const int b = bid / 9, tt = bid % 9;
  const float* Ea = emb + (size_t)(b * 10 + tt) * 128 * 128;
  const float* Eb = Ea + 128 * 128;
  const int t = threadIdx.x;
  for (int i = t; i < 16384; i += 256) {
    const int r = i >> 7, c = i & 127;
    sAT[c * 132 + r] = Ea[i];
    sBT[c * 132 + r] = Eb[i];
  }
  __syncthreads();
  const int tj = t & 15, ti = t >> 4;
  const int n0 = ti * 8, m0 = tj * 8;
  float acc[8][8] = {};
  for (int c = 0; c < 128; ++c) {
    float av[8], bv[8];
    *(float4*)&av[0] = *(const float4*)&sAT[c * 132 + n0];
    *(float4*)&av[4] = *(const float4*)&sAT[c * 132 + n0 + 4];
    *(float4*)&bv[0] = *(const float4*)&sBT[c * 132 + m0];
    *(float4*)&bv[4] = *(const float4*)&sBT[c * 132 + m0 + 4];
#pragma unroll
    for (int ii = 0; ii < 8; ++ii)
#pragma unroll
      for (int jj = 0; jj < 8; ++jj)
        acc[ii][jj] = fmaf(av[ii], bv[jj], acc[ii][jj]);
  }
  float* Og = Aout + (size_t)bid * 16384;
  const float itau = 1.f / 0.07f;
#pragma unroll
  for (int ii = 0; ii < 8; ++ii)
#pragma unroll
    for (int jj = 0; jj < 8; ++jj)
      Og[(n0 + ii) * 128 + m0 + jj] = acc[ii][jj] * itau;
}

// ---------------- S[b,t]=rowsoftmax(A[b,t]); S[b,17-t]=colsoftmax(A[b,t])
__global__ __launch_bounds__(128) void k_softmax(const float* __restrict__ A,
                                                 float* __restrict__ S)
{
  __shared__ float sA[128 * 129];
  __shared__ float s_m[128], s_d[128], s_m2[128], s_d2[128];
  const int bid = blockIdx.x;
  const int b = bid / 9, tt = bid % 9;
  const float* Ag = A + (size_t)bid * 16384;
  const int t = threadIdx.x;
  for (int i = t; i < 16384; i += 128)
    sA[(i >> 7) * 129 + (i & 127)] = Ag[i];
  __syncthreads();
  {
    float m = -1e30f;
    for (int c = 0; c < 128; ++c) m = fmaxf(m, sA[t * 129 + c]);
    float s = 0.f;
    for (int c = 0; c < 128; ++c) s += __expf(sA[t * 129 + c] - m);
    s_m[t] = m; s_d[t] = 1.f / s;
  }
  {
    float m = -1e30f;
    for (int r = 0; r < 128; ++r) m = fmaxf(m, sA[r * 129 + t]);
    float s = 0.f;
    for (int r = 0; r < 128; ++r) s += __expf(sA[r * 129 + t] - m);
    s_m2[t] = m; s_d2[t] = 1.f / s;
  }
  __syncthreads();
  float* Sf = S + (size_t)(b * 18 + tt) * 16384;
  float* Sb = S + (size_t)(b * 18 + 17 - tt) * 16384;
  for (int r = 0; r < 128; ++r) {
    const float v = sA[r * 129 + t];
    Sf[r * 128 + t] = __expf(v - s_m[r]) * s_d[r];
    const float u = sA[t * 129 + r];          // A[c'=t][r'] for backward
    Sb[r * 128 + t] = __expf(u - s_m2[r]) * s_d2[r];
  }
}

// ---------------- chain step: P_k = P_{k-1} @ S[18-k]; F_k = S[k-1] @ F_{k-1};
// At_{k-1} = P_{k-1} @ F_{k-1} with fused column log-softmax diag reduction.
__global__ __launch_bounds__(256) void k_chain(
    int k, const float* __restrict__ S,
    float* __restrict__ Pcur, const float* __restrict__ Pprev,
    float* __restrict__ Fcur, const float* __restrict__ Fprev,
    float* __restrict__ loss)
{
  __shared__ float sLT[128 * 132];   // left matrix, transposed [i][r]
  __shared__ float sR[128 * 36];     // right cols [i][c']
  __shared__ float sAt[32 * 132];    // At tile [c'][r]
  const int role = blockIdx.x >> 5, sub = blockIdx.x & 31;
  const int b = sub >> 2, cb = (sub & 3) * 32;
  const int t = threadIdx.x;
  if (k == 1) {
    if (role == 0) {
      const float* src = S + (size_t)(b * 18 + 17) * 16384;
      float* dst = Pcur + (size_t)b * 16384;
      for (int i = t; i < 4096; i += 256) {
        const int r = i >> 5, c = cb + (i & 31);
        dst[r * 128 + c] = src[r * 128 + c];
      }
    } else if (role == 1) {
      float* dst = Fcur + (size_t)b * 16384;
      for (int i = t; i < 4096; i += 256) {
        const int r = i >> 5, c = cb + (i & 31);
        dst[r * 128 + c] = (r == c) ? 1.f : 0.f;
      }
    }
    return;
  }
  const float* L; const float* R;
  if (role == 0) {
    if (k > 8) return;
    L = Pprev + (size_t)b * 16384;
    R = S + (size_t)(b * 18 + 18 - k) * 16384;
  } else if (role == 1) {
    if (k > 8) return;
    L = S + (size_t)(b * 18 + k - 1) * 16384;
    R = Fprev + (size_t)b * 16384;
  } else {
    L = Pprev + (size_t)b * 16384;
    R = Fprev + (size_t)b * 16384;
  }
  for (int i = t; i < 16384; i += 256) sLT[(i & 127) * 132 + (i >> 7)] = L[i];
  for (int i = t; i < 4096; i += 256) {
    const int r = i >> 5, c = i & 31;
    sR[r * 36 + c] = R[r * 128 + cb + c];
  }
  __syncthreads();
  const int tc = t & 7, tr = t >> 3;
  const int c0 = tc * 4, r0 = tr * 4;
  float acc[4][4] = {};
  for (int i = 0; i < 128; ++i) {
    float a[4], bb[4];
    *(float4*)&a[0] = *(const float4*)&sLT[i * 132 + r0];
    *(float4*)&bb[0] = *(const float4*)&sR[i * 36 + c0];
#pragma unroll
    for (int ii = 0; ii < 4; ++ii)
#pragma unroll
      for (int jj = 0; jj < 4; ++jj)
        acc[ii][jj] = fmaf(a[ii], bb[jj], acc[ii][jj]);
  }
  if (role < 2) {
    float* dst = (role == 0 ? Pcur : Fcur) + (size_t)b * 16384;
#pragma unroll
    for (int ii = 0; ii < 4; ++ii)
#pragma unroll
      for (int jj = 0; jj < 4; ++jj)
        dst[(r0 + ii) * 128 + cb + c0 + jj] = acc[ii][jj];
  } else {
#pragma unroll
    for (int ii = 0; ii < 4; ++ii)
#pragma unroll
      for (int jj = 0; jj < 4; ++jj)
        sAt[(c0 + jj) * 132 + r0 + ii] = acc[ii][jj];
    __syncthreads();
    if (t < 32) {
      const int jg = cb + t;   // global column / diag index
      float m = -1e30f;
      for (int r = 0; r < 128; ++r) m = fmaxf(m, sAt[t * 132 + r]);
      float s = 0.f;
      for (int r = 0; r < 128; ++r) s += __expf(sAt[t * 132 + r] - m);
      float lp = sAt[t * 132 + jg] - m - __logf(s);
#pragma unroll
      for (int off = 1; off < 32; off <<= 1) lp += __shfl_xor(lp, off, 32);
      if (t == 0) atomicAdd(loss, lp);
    }
  }
}

__global__ void k_final(const float* __restrict__ acc, float* __restrict__ out) {
  out[0] = -acc[0] * (1.f / 131072.f);   // /(B*N) mean then /N
}

extern "C" void kernel_launch(void* const* d_in, const int* in_sizes, int n_in,
                              void* d_out, int out_size, void* d_ws, size_t ws_size,
                              hipStream_t stream) {
  const float* seq = (const float*)d_in[0];
  const float* w1  = (const float*)d_in[1];
  const float* b1  = (const float*)d_in[2];
  const float* w2  = (const float*)d_in[3];
  const float* b2  = (const float*)d_in[4];
  const float* lw  = (const float*)d_in[5];
  const float* lb  = (const float*)d_in[6];
  float* out = (float*)d_out;
  float* ws  = (float*)d_ws;

  float* emb  = ws;                 // 10240*128
  float* S    = emb + 1310720;      // 8*18*128*128
  float* Pb   = S + 2359296;        // 2 slots * 8*128*128
  float* Fb   = Pb + 262144;        // 2 slots
  float* w2p  = Fb + 262144;        // 18432
  float* lossAcc = w2p + 18432;     // 1

  float* Aout = out + 1;

  k_repack<<<72, 256, 0, stream>>>(w2, w2p, lossAcc);
  k_encoder<<<10240, 256, 0, stream>>>(seq, w1, b1, w2p, b2, lw, lb, emb);
  k_affinity<<<72, 256, 0, stream>>>(emb, Aout);
  k_softmax<<<72, 128, 0, stream>>>(Aout, S);
  for (int k = 1; k <= 9; ++k) {
    const int cur = k & 1, prev = cur ^ 1;
    k_chain<<<96, 256, 0, stream>>>(k, S,
        Pb + cur * 131072, Pb + prev * 131072,
        Fb + cur * 131072, Fb + prev * 131072,
        lossAcc);
  }
  k_final<<<1, 1, 0, stream>>>(lossAcc, out);
}

// Round 3
// 353.008 us; speedup vs baseline: 4.2542x; 4.2542x over previous
//
#include <hip/hip_runtime.h>
#include <math.h>

typedef _Float16 f16;
typedef f16 f16x8 __attribute__((ext_vector_type(8)));
typedef float f32x4 __attribute__((ext_vector_type(4)));

// ---------------- repack conv2 weights -> f16 hi/lo, layout [h/l][tap][oc][ic]
__global__ __launch_bounds__(256) void k_repack(const float* __restrict__ w2,
                                                f16* __restrict__ w2p,
                                                float* __restrict__ lossAcc) {
  if (blockIdx.x == 0 && threadIdx.x == 0) lossAcc[0] = 0.f;
  int i = blockIdx.x * 256 + threadIdx.x;
  if (i < 18432) {
    const int ic = i & 31, oc = (i >> 5) & 63, tap = i >> 11;
    const float w = w2[oc * 288 + ic * 9 + tap];
    const f16 wh = (f16)w;
    w2p[i] = wh;
    w2p[18432 + i] = (f16)(w - (float)wh);
  }
}

// ---------------- fused encoder: conv1(fp32 VALU) -> conv2(f16 MFMA, Bh+Bl) -> pool -> linear -> L2norm
__global__ __launch_bounds__(256, 4) void k_encoder(
    const float* __restrict__ seq,
    const float* __restrict__ w1, const float* __restrict__ b1,
    const f16* __restrict__ w2p, const float* __restrict__ b2,
    const float* __restrict__ lw, const float* __restrict__ lb,
    float* __restrict__ emb)
{
  __shared__ float s_in[33 * 33];
  __shared__ float s_w1[288];
  __shared__ __align__(16) f16 s_h1[289 * 40];  // rows = iy*17+ix; 80B stride; zero rows for pads
  __shared__ float s_pool[64];
  __shared__ float s_part[2];
  const int t = threadIdx.x;
  const int lane = t & 63, wv = t >> 6;   // wave = oc-group of 16

  // stage input 32x32 into padded 33x33 (zero row/col 32)
  const float* x = seq + (size_t)blockIdx.x * 1024;
  for (int i = t; i < 1024; i += 256)
    s_in[(i >> 5) * 33 + (i & 31)] = x[i];
  if (t < 33) s_in[32 * 33 + t] = 0.f;
  if (t < 32) s_in[t * 33 + 32] = 0.f;
  for (int i = t; i < 288; i += 256) s_w1[i] = w1[i];
  // zero pad rows of h1: ix==16 slots (16 rows) + iy==16 region (rows 272..288)
  if (t < 132) {
    const int zi = t >> 2, ch = t & 3;
    const int row = (zi < 16) ? zi * 17 + 16 : 272 + (zi - 16);
    *(f32x4*)&s_h1[row * 40 + ch * 8] = f32x4{0.f, 0.f, 0.f, 0.f};
  }
  __syncthreads();

  // conv1: thread = one of 16x16 output positions, 32 oc in fp32, store f16 to LDS
  {
    const int oy = t >> 4, ox = t & 15;
    float p[9];
#pragma unroll
    for (int dy = 0; dy < 3; ++dy)
#pragma unroll
      for (int dx = 0; dx < 3; ++dx)
        p[dy * 3 + dx] = s_in[(2 * oy + dy) * 33 + 2 * ox + dx];
    const int row = oy * 17 + ox;
#pragma unroll
    for (int c = 0; c < 4; ++c) {
      f16x8 pk;
#pragma unroll
      for (int j = 0; j < 8; ++j) {
        const int oc = c * 8 + j;
        float a = b1[oc];
#pragma unroll
        for (int q = 0; q < 9; ++q) a = fmaf(p[q], s_w1[oc * 9 + q], a);
        pk[j] = (f16)fmaxf(a, 0.f);
      }
      *(f16x8*)&s_h1[row * 40 + c * 8] = pk;
    }
  }

  // preload conv2 B-fragments (hi/lo) into registers: wave wv owns oc 16*wv..+16
  f16x8 bh[9], bl[9];
  float bias;
  {
    const int oc = wv * 16 + (lane & 15);
    const int o8 = ((lane >> 4) & 3) * 8;
#pragma unroll
    for (int tap = 0; tap < 9; ++tap) {
      bh[tap] = *(const f16x8*)(w2p + ((tap * 64 + oc) * 32 + o8));
      bl[tap] = *(const f16x8*)(w2p + 18432 + ((tap * 64 + oc) * 32 + o8));
    }
    bias = b2[wv * 16 + (lane & 15)];
  }
  __syncthreads();

  // conv2 via mfma_f32_16x16x32_f16: M=64 pos (4 tiles), N=16 oc (this wave), K=32 ic per tap
  {
    const int lr = lane & 15, o8 = (lane >> 4) & 3;
    f32x4 acc[4];
#pragma unroll
    for (int m = 0; m < 4; ++m) acc[m] = f32x4{bias, bias, bias, bias};
#pragma unroll
    for (int m = 0; m < 4; ++m) {
      const int opos = m * 16 + lr, oy = opos >> 3, ox = opos & 7;
      const int baddr = (34 * oy + 2 * ox) * 40 + o8 * 8;  // f16 units
#pragma unroll
      for (int dy = 0; dy < 3; ++dy)
#pragma unroll
        for (int dx = 0; dx < 3; ++dx) {
          const int tap = dy * 3 + dx;
          f16x8 afr = *(const f16x8*)&s_h1[baddr + (dy * 17 + dx) * 40];
          acc[m] = __builtin_amdgcn_mfma_f32_16x16x32_f16(afr, bh[tap], acc[m], 0, 0, 0);
          acc[m] = __builtin_amdgcn_mfma_f32_16x16x32_f16(afr, bl[tap], acc[m], 0, 0, 0);
        }
    }
    // relu + avgpool: C layout col=lane&15(oc), row=(lane>>4)*4+v + 16m (pos)
    float s = 0.f;
#pragma unroll
    for (int m = 0; m < 4; ++m)
#pragma unroll
      for (int v = 0; v < 4; ++v) s += fmaxf(acc[m][v], 0.f);
    s += __shfl_xor(s, 16, 64);
    s += __shfl_xor(s, 32, 64);
    if (lane < 16) s_pool[wv * 16 + lane] = s * (1.f / 64.f);
  }
  __syncthreads();

  // linear 64->128 + L2 normalize
  float val = 0.f;
  if (t < 128) {
    val = lb[t];
#pragma unroll 8
    for (int c = 0; c < 64; ++c) val = fmaf(s_pool[c], lw[c * 128 + t], val);
  }
  float sq = val * val;
#pragma unroll
  for (int off = 1; off < 64; off <<= 1) sq += __shfl_xor(sq, off, 64);
  if (t < 128 && (t & 63) == 0) s_part[t >> 6] = sq;
  __syncthreads();
  if (t < 128) {
    const float nrm = sqrtf(s_part[0] + s_part[1]);
    const float scale = 1.f / fmaxf(nrm, 1e-12f);
    emb[(size_t)blockIdx.x * 128 + t] = val * scale;
  }
}

// ---------------- A[b,t] = emb[b,t] @ emb[b,t+1]^T / tau  -> d_out+1
__global__ __launch_bounds__(256) void k_affinity(
    const float* __restrict__ emb, float* __restrict__ Aout)
{
  __shared__ float sAT[128 * 132];
  __shared__ float sBT[128 * 132];
  const int bid = blockIdx.x;
  const int b = bid / 9, tt = bid % 9;
  const float* Ea = emb + (size_t)(b * 10 + tt) * 128 * 128;
  const float* Eb = Ea + 128 * 128;
  const int t = threadIdx.x;
  for (int i = t; i < 16384; i += 256) {
    const int r = i >> 7, c = i & 127;
    sAT[c * 132 + r] = Ea[i];
    sBT[c * 132 + r] = Eb[i];
  }
  __syncthreads();
  const int tj = t & 15, ti = t >> 4;
  const int n0 = ti * 8, m0 = tj * 8;
  float acc[8][8] = {};
  for (int c = 0; c < 128; ++c) {
    float av[8], bv[8];
    *(float4*)&av[0] = *(const float4*)&sAT[c * 132 + n0];
    *(float4*)&av[4] = *(const float4*)&sAT[c * 132 + n0 + 4];
    *(float4*)&bv[0] = *(const float4*)&sBT[c * 132 + m0];
    *(float4*)&bv[4] = *(const float4*)&sBT[c * 132 + m0 + 4];
#pragma unroll
    for (int ii = 0; ii < 8; ++ii)
#pragma unroll
      for (int jj = 0; jj < 8; ++jj)
        acc[ii][jj] = fmaf(av[ii], bv[jj], acc[ii][jj]);
  }
  float* Og = Aout + (size_t)bid * 16384;
  const float itau = 1.f / 0.07f;
#pragma unroll
  for (int ii = 0; ii < 8; ++ii)
#pragma unroll
    for (int jj = 0; jj < 8; ++jj)
      Og[(n0 + ii) * 128 + m0 + jj] = acc[ii][jj] * itau;
}

// ---------------- S[b,t]=rowsoftmax(A[b,t]); S[b,17-t]=colsoftmax(A[b,t])
__global__ __launch_bounds__(128) void k_softmax(const float* __restrict__ A,
                                                 float* __restrict__ S)
{
  __shared__ float sA[128 * 129];
  __shared__ float s_m[128], s_d[128], s_m2[128], s_d2[128];
  const int bid = blockIdx.x;
  const int b = bid / 9, tt = bid % 9;
  const float* Ag = A + (size_t)bid * 16384;
  const int t = threadIdx.x;
  for (int i = t; i < 16384; i += 128)
    sA[(i >> 7) * 129 + (i & 127)] = Ag[i];
  __syncthreads();
  {
    float m = -1e30f;
    for (int c = 0; c < 128; ++c) m = fmaxf(m, sA[t * 129 + c]);
    float s = 0.f;
    for (int c = 0; c < 128; ++c) s += expf(sA[t * 129 + c] - m);
    s_m[t] = m; s_d[t] = 1.f / s;
  }
  {
    float m = -1e30f;
    for (int r = 0; r < 128; ++r) m = fmaxf(m, sA[r * 129 + t]);
    float s = 0.f;
    for (int r = 0; r < 128; ++r) s += expf(sA[r * 129 + t] - m);
    s_m2[t] = m; s_d2[t] = 1.f / s;
  }
  __syncthreads();
  float* Sf = S + (size_t)(b * 18 + tt) * 16384;
  float* Sb = S + (size_t)(b * 18 + 17 - tt) * 16384;
  for (int r = 0; r < 128; ++r) {
    const float v = sA[r * 129 + t];
    Sf[r * 128 + t] = expf(v - s_m[r]) * s_d[r];
    const float u = sA[t * 129 + r];
    Sb[r * 128 + t] = expf(u - s_m2[r]) * s_d2[r];
  }
}

// ---------------- chain step (P/F ladder) + fused col-logsoftmax diag loss
__global__ __launch_bounds__(256) void k_chain(
    int k, const float* __restrict__ S,
    float* __restrict__ Pcur, const float* __restrict__ Pprev,
    float* __restrict__ Fcur, const float* __restrict__ Fprev,
    float* __restrict__ loss)
{
  __shared__ float sLT[128 * 132];
  __shared__ float sR[128 * 36];
  __shared__ float sAt[32 * 132];
  const int role = blockIdx.x >> 5, sub = blockIdx.x & 31;
  const int b = sub >> 2, cb = (sub & 3) * 32;
  const int t = threadIdx.x;
  if (k == 1) {
    if (role == 0) {
      const float* src = S + (size_t)(b * 18 + 17) * 16384;
      float* dst = Pcur + (size_t)b * 16384;
      for (int i = t; i < 4096; i += 256) {
        const int r = i >> 5, c = cb + (i & 31);
        dst[r * 128 + c] = src[r * 128 + c];
      }
    } else if (role == 1) {
      float* dst = Fcur + (size_t)b * 16384;
      for (int i = t; i < 4096; i += 256) {
        const int r = i >> 5, c = cb + (i & 31);
        dst[r * 128 + c] = (r == c) ? 1.f : 0.f;
      }
    }
    return;
  }
  const float* L; const float* R;
  if (role == 0) {
    if (k > 8) return;
    L = Pprev + (size_t)b * 16384;
    R = S + (size_t)(b * 18 + 18 - k) * 16384;
  } else if (role == 1) {
    if (k > 8) return;
    L = S + (size_t)(b * 18 + k - 1) * 16384;
    R = Fprev + (size_t)b * 16384;
  } else {
    L = Pprev + (size_t)b * 16384;
    R = Fprev + (size_t)b * 16384;
  }
  for (int i = t; i < 16384; i += 256) sLT[(i & 127) * 132 + (i >> 7)] = L[i];
  for (int i = t; i < 4096; i += 256) {
    const int r = i >> 5, c = i & 31;
    sR[r * 36 + c] = R[r * 128 + cb + c];
  }
  __syncthreads();
  const int tc = t & 7, tr = t >> 3;
  const int c0 = tc * 4, r0 = tr * 4;
  float acc[4][4] = {};
  for (int i = 0; i < 128; ++i) {
    float a[4], bb[4];
    *(float4*)&a[0] = *(const float4*)&sLT[i * 132 + r0];
    *(float4*)&bb[0] = *(const float4*)&sR[i * 36 + c0];
#pragma unroll
    for (int ii = 0; ii < 4; ++ii)
#pragma unroll
      for (int jj = 0; jj < 4; ++jj)
        acc[ii][jj] = fmaf(a[ii], bb[jj], acc[ii][jj]);
  }
  if (role < 2) {
    float* dst = (role == 0 ? Pcur : Fcur) + (size_t)b * 16384;
#pragma unroll
    for (int ii = 0; ii < 4; ++ii)
#pragma unroll
      for (int jj = 0; jj < 4; ++jj)
        dst[(r0 + ii) * 128 + cb + c0 + jj] = acc[ii][jj];
  } else {
#pragma unroll
    for (int ii = 0; ii < 4; ++ii)
#pragma unroll
      for (int jj = 0; jj < 4; ++jj)
        sAt[(c0 + jj) * 132 + r0 + ii] = acc[ii][jj];
    __syncthreads();
    if (t < 32) {
      const int jg = cb + t;
      float m = -1e30f;
      for (int r = 0; r < 128; ++r) m = fmaxf(m, sAt[t * 132 + r]);
      float s = 0.f;
      for (int r = 0; r < 128; ++r) s += expf(sAt[t * 132 + r] - m);
      float lp = sAt[t * 132 + jg] - m - logf(s);
#pragma unroll
      for (int off = 1; off < 32; off <<= 1) lp += __shfl_xor(lp, off, 32);
      if (t == 0) atomicAdd(loss, lp);
    }
  }
}

__global__ void k_final(const float* __restrict__ acc, float* __restrict__ out) {
  out[0] = -acc[0] * (1.f / 131072.f);
}

extern "C" void kernel_launch(void* const* d_in, const int* in_sizes, int n_in,
                              void* d_out, int out_size, void* d_ws, size_t ws_size,
                              hipStream_t stream) {
  const float* seq = (const float*)d_in[0];
  const float* w1  = (const float*)d_in[1];
  const float* b1  = (const float*)d_in[2];
  const float* w2  = (const float*)d_in[3];
  const float* b2  = (const float*)d_in[4];
  const float* lw  = (const float*)d_in[5];
  const float* lb  = (const float*)d_in[6];
  float* out = (float*)d_out;
  float* ws  = (float*)d_ws;

  float* emb  = ws;                 // 10240*128
  float* S    = emb + 1310720;      // 8*18*128*128
  float* Pb   = S + 2359296;        // 2 slots * 8*128*128
  float* Fb   = Pb + 262144;        // 2 slots
  f16*   w2p  = (f16*)(Fb + 262144);  // 2*18432 f16 = 73728B
  float* lossAcc = (float*)(w2p + 36864);

  float* Aout = out + 1;

  k_repack<<<72, 256, 0, stream>>>(w2, w2p, lossAcc);
  k_encoder<<<10240, 256, 0, stream>>>(seq, w1, b1, w2p, b2, lw, lb, emb);
  k_affinity<<<72, 256, 0, stream>>>(emb, Aout);
  k_softmax<<<72, 128, 0, stream>>>(Aout, S);
  for (int k = 1; k <= 9; ++k) {
    const int cur = k & 1, prev = cur ^ 1;
    k_chain<<<96, 256, 0, stream>>>(k, S,
        Pb + cur * 131072, Pb + prev * 131072,
        Fb + cur * 131072, Fb + prev * 131072,
        lossAcc);
  }
  k_final<<<1, 1, 0, stream>>>(lossAcc, out);
}

// Round 4
// 294.064 us; speedup vs baseline: 5.1069x; 1.2004x over previous
//
#include <hip/hip_runtime.h>
#include <math.h>

typedef _Float16 f16;
typedef f16 f16x8 __attribute__((ext_vector_type(8)));
typedef f16 f16x4 __attribute__((ext_vector_type(4)));
typedef float f32x4 __attribute__((ext_vector_type(4)));

// ---------------- repack: conv2 weights -> f16 hi/lo [h/l][tap][oc][ic]; lw -> lwT; zero loss
__global__ __launch_bounds__(256) void k_repack(const float* __restrict__ w2,
                                                const float* __restrict__ lw,
                                                f16* __restrict__ w2p,
                                                float* __restrict__ lwT,
                                                float* __restrict__ lossAcc) {
  int i = blockIdx.x * 256 + threadIdx.x;
  if (i == 0) lossAcc[0] = 0.f;
  if (i < 18432) {
    const int ic = i & 31, oc = (i >> 5) & 63, tap = i >> 11;
    const float w = w2[oc * 288 + ic * 9 + tap];
    const f16 wh = (f16)w;
    w2p[i] = wh;
    w2p[18432 + i] = (f16)(w - (float)wh);
  }
  if (i < 8192) lwT[i] = lw[(i & 63) * 128 + (i >> 6)];  // lwT[o][c] = lw[c][o]
}

// ---------------- fused encoder
__global__ __launch_bounds__(256, 4) void k_encoder(
    const float* __restrict__ seq,
    const float* __restrict__ w1, const float* __restrict__ b1,
    const f16* __restrict__ w2p, const float* __restrict__ b2,
    const float* __restrict__ lwT, const float* __restrict__ lb,
    f16* __restrict__ emb16)
{
  __shared__ float s_in[33 * 33];
  __shared__ __align__(16) f16 s_h1[289 * 40];  // row = iy*17+ix, 80B stride, pad rows zeroed
  __shared__ __align__(16) float s_pool[64];
  __shared__ float s_part[2];
  const int t = threadIdx.x;
  const int lane = t & 63, wv = t >> 6;
  const int wvs = __builtin_amdgcn_readfirstlane(wv);

  const float* x = seq + (size_t)blockIdx.x * 1024;
  for (int i = t; i < 1024; i += 256)
    s_in[(i >> 5) * 33 + (i & 31)] = x[i];
  if (t < 33) s_in[32 * 33 + t] = 0.f;
  if (t < 32) s_in[t * 33 + 32] = 0.f;
  if (t < 132) {
    const int zi = t >> 2, ch = t & 3;
    const int row = (zi < 16) ? zi * 17 + 16 : 272 + (zi - 16);
    *(f32x4*)&s_h1[row * 40 + ch * 8] = f32x4{0.f, 0.f, 0.f, 0.f};
  }
  // conv1 weights for this wave's 8 oc -> SGPRs
  float cw[8][9], cb[8];
  {
    const float* wp = w1 + wvs * 72;
#pragma unroll
    for (int j = 0; j < 8; ++j) {
#pragma unroll
      for (int q = 0; q < 9; ++q)
        cw[j][q] = __uint_as_float(__builtin_amdgcn_readfirstlane(__float_as_uint(wp[j * 9 + q])));
      cb[j] = __uint_as_float(__builtin_amdgcn_readfirstlane(__float_as_uint(b1[wvs * 8 + j])));
    }
  }
  __syncthreads();
  // conv1: wave wv -> oc [8wv,8wv+8), lane covers 4 positions
#pragma unroll
  for (int i = 0; i < 4; ++i) {
    const int pos = lane + 64 * i, oy = pos >> 4, ox = pos & 15;
    float p[9];
#pragma unroll
    for (int dy = 0; dy < 3; ++dy)
#pragma unroll
      for (int dx = 0; dx < 3; ++dx)
        p[dy * 3 + dx] = s_in[(2 * oy + dy) * 33 + 2 * ox + dx];
    f16x8 o;
#pragma unroll
    for (int j = 0; j < 8; ++j) {
      float a = cb[j];
#pragma unroll
      for (int q = 0; q < 9; ++q) a = fmaf(p[q], cw[j][q], a);
      o[j] = (f16)fmaxf(a, 0.f);
    }
    *(f16x8*)&s_h1[(oy * 17 + ox) * 40 + 8 * wv] = o;
  }
  // conv2 B-fragments (hi/lo) into registers
  f16x8 bh[9], bl[9];
  float bias2;
  {
    const int oc = wv * 16 + (lane & 15);
    const int o8 = ((lane >> 4) & 3) * 8;
#pragma unroll
    for (int tap = 0; tap < 9; ++tap) {
      bh[tap] = *(const f16x8*)(w2p + ((tap * 64 + oc) * 32 + o8));
      bl[tap] = *(const f16x8*)(w2p + 18432 + ((tap * 64 + oc) * 32 + o8));
    }
    bias2 = b2[wv * 16 + (lane & 15)];
  }
  __syncthreads();
  // conv2 MFMA
  {
    const int lr = lane & 15, o8 = (lane >> 4) & 3;
    f32x4 acc[4];
#pragma unroll
    for (int m = 0; m < 4; ++m) acc[m] = f32x4{bias2, bias2, bias2, bias2};
#pragma unroll
    for (int m = 0; m < 4; ++m) {
      const int opos = m * 16 + lr, oy = opos >> 3, ox = opos & 7;
      const int baddr = (34 * oy + 2 * ox) * 40 + o8 * 8;
#pragma unroll
      for (int dy = 0; dy < 3; ++dy)
#pragma unroll
        for (int dx = 0; dx < 3; ++dx) {
          const int tap = dy * 3 + dx;
          f16x8 afr = *(const f16x8*)&s_h1[baddr + (dy * 17 + dx) * 40];
          acc[m] = __builtin_amdgcn_mfma_f32_16x16x32_f16(afr, bh[tap], acc[m], 0, 0, 0);
          acc[m] = __builtin_amdgcn_mfma_f32_16x16x32_f16(afr, bl[tap], acc[m], 0, 0, 0);
        }
    }
    float s = 0.f;
#pragma unroll
    for (int m = 0; m < 4; ++m)
#pragma unroll
      for (int v = 0; v < 4; ++v) s += fmaxf(acc[m][v], 0.f);
    s += __shfl_xor(s, 16, 64);
    s += __shfl_xor(s, 32, 64);
    if (lane < 16) s_pool[wv * 16 + lane] = s * (1.f / 64.f);
  }
  __syncthreads();
  // linear 64->128 + L2 normalize, f16 out
  float val = 0.f;
  if (t < 128) {
    val = lb[t];
    const float* lr = lwT + t * 64;
#pragma unroll
    for (int c4 = 0; c4 < 16; ++c4) {
      const f32x4 wv4 = *(const f32x4*)(lr + c4 * 4);
      const f32x4 pv = *(const f32x4*)&s_pool[c4 * 4];
      val = fmaf(pv[0], wv4[0], val);
      val = fmaf(pv[1], wv4[1], val);
      val = fmaf(pv[2], wv4[2], val);
      val = fmaf(pv[3], wv4[3], val);
    }
  }
  float sq = val * val;
#pragma unroll
  for (int off = 1; off < 64; off <<= 1) sq += __shfl_xor(sq, off, 64);
  if (t < 128 && (t & 63) == 0) s_part[t >> 6] = sq;
  __syncthreads();
  if (t < 128) {
    const float nrm = sqrtf(s_part[0] + s_part[1]);
    emb16[(size_t)blockIdx.x * 128 + t] = (f16)(val / fmaxf(nrm, 1e-12f));
  }
}

// ---------------- affinity via MFMA: A[b,t] = Ea @ Eb^T / tau (fp32 out)
__global__ __launch_bounds__(256) void k_affinity(const f16* __restrict__ emb16,
                                                  float* __restrict__ Aout)
{
  __shared__ __align__(16) f16 sL[16384];
  __shared__ __align__(16) f16 sR[16384];
  const int bid = blockIdx.x, b = bid / 9, tt = bid % 9;
  const int t = threadIdx.x, lane = t & 63, w = t >> 6;
  const int lr = lane & 15, lg = lane >> 4;
  const f16* Ea = emb16 + (size_t)(b * 10 + tt) * 16384;
  const f16* Eb = Ea + 16384;
#pragma unroll
  for (int j = 0; j < 8; ++j) {
    const int ck = j * 256 + t, row = ck >> 4, c16 = ck & 15;
    const int off = ((row << 8) + (c16 << 4)) ^ ((row & 7) << 4);
    *(f16x8*)((char*)sL + off) = *(const f16x8*)(Ea + ck * 8);
    *(f16x8*)((char*)sR + off) = *(const f16x8*)(Eb + ck * 8);
  }
  __syncthreads();
  f32x4 acc[2][8] = {};
#pragma unroll
  for (int kt = 0; kt < 4; ++kt) {
    int row = w * 32 + lr;
    int byt = ((row << 8) + kt * 64 + (lg << 4)) ^ ((row & 7) << 4);
    const f16x8 a0 = *(const f16x8*)((char*)sL + byt);
    row += 16;
    byt = ((row << 8) + kt * 64 + (lg << 4)) ^ ((row & 7) << 4);
    const f16x8 a1 = *(const f16x8*)((char*)sL + byt);
#pragma unroll
    for (int nt = 0; nt < 8; ++nt) {
      const int rb = nt * 16 + lr;
      const int bb = ((rb << 8) + kt * 64 + (lg << 4)) ^ ((rb & 7) << 4);
      const f16x8 bv = *(const f16x8*)((char*)sR + bb);
      acc[0][nt] = __builtin_amdgcn_mfma_f32_16x16x32_f16(a0, bv, acc[0][nt], 0, 0, 0);
      acc[1][nt] = __builtin_amdgcn_mfma_f32_16x16x32_f16(a1, bv, acc[1][nt], 0, 0, 0);
    }
  }
  float* Og = Aout + (size_t)bid * 16384;
#pragma unroll
  for (int mt = 0; mt < 2; ++mt)
#pragma unroll
    for (int nt = 0; nt < 8; ++nt)
#pragma unroll
      for (int v = 0; v < 4; ++v) {
        const int r = w * 32 + mt * 16 + lg * 4 + v, c = nt * 16 + lr;
        Og[r * 128 + c] = acc[mt][nt][v] * (1.f / 0.07f);
      }
}

// ---------------- softmax: Srow[j=tt]=rowsm(A), Srow[j=17-tt]=colsm(A)^T, + transposed copies; loss_1 at tt==0
__global__ __launch_bounds__(128) void k_softmax(const float* __restrict__ A,
                                                 f16* __restrict__ Srow, f16* __restrict__ ST,
                                                 float* __restrict__ loss)
{
  __shared__ __align__(16) f16 sT[128 * 136];
  __shared__ float s_m[128], s_d[128], s_m2[128], s_d2[128];
  __shared__ float s_red[2];
  const int bid = blockIdx.x, b = bid / 9, tt = bid % 9;
  const float* Ag = A + (size_t)bid * 16384;
  const int t = threadIdx.x;
  float m1 = -1e30f, m2 = -1e30f, s1 = 0.f, s2 = 0.f;
#pragma unroll 4
  for (int r = 0; r < 128; ++r) {
    m2 = fmaxf(m2, Ag[r * 128 + t]);   // col t
    m1 = fmaxf(m1, Ag[t * 128 + r]);   // row t
  }
#pragma unroll 4
  for (int r = 0; r < 128; ++r) {
    s2 += expf(Ag[r * 128 + t] - m2);
    s1 += expf(Ag[t * 128 + r] - m1);
  }
  s_m[t] = m1; s_d[t] = 1.f / s1;
  s_m2[t] = m2; s_d2[t] = 1.f / s2;
  __syncthreads();
  f16* Sfg = Srow + (size_t)(b * 18 + tt) * 16384;
  f16* SfTg = ST + (size_t)(b * 18 + tt) * 16384;
  f16* Sbg = Srow + (size_t)(b * 18 + 17 - tt) * 16384;
  f16* SbTg = ST + (size_t)(b * 18 + 17 - tt) * 16384;
  // Sf pass
  for (int r = 0; r < 128; ++r) {
    const float v1 = expf(Ag[r * 128 + t] - s_m[r]) * s_d[r];
    Sfg[r * 128 + t] = (f16)v1;
    sT[t * 136 + r] = (f16)v1;
  }
  __syncthreads();
#pragma unroll
  for (int j = 0; j < 16; ++j) {
    const int ck = j * 128 + t, c = ck >> 4, c16 = ck & 15;
    *(f16x8*)(SfTg + ck * 8) = *(const f16x8*)&sT[c * 136 + c16 * 8];
  }
  __syncthreads();
  // Sb pass (+ loss_1 for tt==0: At_1 = S_17 = Sb; values in [0,1] so no max shift needed)
  float s3 = 0.f, d3 = 0.f;
  for (int r = 0; r < 128; ++r) {
    const float v2 = expf(Ag[t * 128 + r] - s_m2[r]) * s_d2[r];
    Sbg[r * 128 + t] = (f16)v2;
    sT[t * 136 + r] = (f16)v2;
    if (tt == 0) {
      s3 += expf(v2);
      if (r == t) d3 = v2;
    }
  }
  __syncthreads();
#pragma unroll
  for (int j = 0; j < 16; ++j) {
    const int ck = j * 128 + t, c = ck >> 4, c16 = ck & 15;
    *(f16x8*)(SbTg + ck * 8) = *(const f16x8*)&sT[c * 136 + c16 * 8];
  }
  if (tt == 0) {
    float lp = d3 - logf(s3);
#pragma unroll
    for (int off = 1; off < 64; off <<= 1) lp += __shfl_xor(lp, off, 64);
    if ((t & 63) == 0) s_red[t >> 6] = lp;
    __syncthreads();
    if (t == 0) atomicAdd(loss, s_red[0] + s_red[1]);
  }
}

// ---------------- chain step: MFMA f16 ladder + fused loss
// role0: P_k = P_{k-1} @ S_{18-k}   (k<=8)  -> Prow
// role1: F_k = S_{k-1} @ F_{k-1}    (3<=k<=8) -> FT (transposed)
// role2: At_{k-1} = P_{k-1} @ F_{k-1} (k>=3) -> column log-softmax diag loss
__global__ __launch_bounds__(256) void k_chain(
    int k,
    const f16* __restrict__ Srow, const f16* __restrict__ ST,
    f16* __restrict__ Pcur, const f16* __restrict__ Pprev,
    f16* __restrict__ FTcur, const f16* __restrict__ FTprev,
    float* __restrict__ loss)
{
  __shared__ __align__(16) f16 sL[16384];
  __shared__ __align__(16) f16 sRt[16384];
  const int role = blockIdx.x >> 3, b = blockIdx.x & 7;
  const int t = threadIdx.x, lane = t & 63, w = t >> 6;
  const int lr = lane & 15, lg = lane >> 4;

  const f16 *L, *Rt;
  if (role == 0) {
    if (k > 8) return;
    L = (k == 2) ? (Srow + (size_t)(b * 18 + 17) * 16384) : (Pprev + (size_t)b * 16384);
    Rt = ST + (size_t)(b * 18 + (18 - k)) * 16384;
  } else if (role == 1) {
    if (k < 3 || k > 8) return;
    L = Srow + (size_t)(b * 18 + (k - 1)) * 16384;
    Rt = (k == 3) ? (ST + (size_t)(b * 18 + 1) * 16384) : (FTprev + (size_t)b * 16384);
  } else {
    if (k < 3) return;
    L = Pprev + (size_t)b * 16384;
    Rt = (k == 3) ? (ST + (size_t)(b * 18 + 1) * 16384) : (FTprev + (size_t)b * 16384);
  }
#pragma unroll
  for (int j = 0; j < 8; ++j) {
    const int ck = j * 256 + t, row = ck >> 4, c16 = ck & 15;
    const int off = ((row << 8) + (c16 << 4)) ^ ((row & 7) << 4);
    *(f16x8*)((char*)sL + off) = *(const f16x8*)(L + ck * 8);
    *(f16x8*)((char*)sRt + off) = *(const f16x8*)(Rt + ck * 8);
  }
  __syncthreads();
  f32x4 acc[2][8] = {};
#pragma unroll
  for (int kt = 0; kt < 4; ++kt) {
    int row = w * 32 + lr;
    int byt = ((row << 8) + kt * 64 + (lg << 4)) ^ ((row & 7) << 4);
    const f16x8 a0 = *(const f16x8*)((char*)sL + byt);
    row += 16;
    byt = ((row << 8) + kt * 64 + (lg << 4)) ^ ((row & 7) << 4);
    const f16x8 a1 = *(const f16x8*)((char*)sL + byt);
#pragma unroll
    for (int nt = 0; nt < 8; ++nt) {
      const int rb = nt * 16 + lr;
      const int bb = ((rb << 8) + kt * 64 + (lg << 4)) ^ ((rb & 7) << 4);
      const f16x8 bv = *(const f16x8*)((char*)sRt + bb);
      acc[0][nt] = __builtin_amdgcn_mfma_f32_16x16x32_f16(a0, bv, acc[0][nt], 0, 0, 0);
      acc[1][nt] = __builtin_amdgcn_mfma_f32_16x16x32_f16(a1, bv, acc[1][nt], 0, 0, 0);
    }
  }
  if (role == 0) {
    f16* P = Pcur + (size_t)b * 16384;
#pragma unroll
    for (int mt = 0; mt < 2; ++mt)
#pragma unroll
      for (int nt = 0; nt < 8; ++nt)
#pragma unroll
        for (int v = 0; v < 4; ++v)
          P[(w * 32 + mt * 16 + lg * 4 + v) * 128 + nt * 16 + lr] = (f16)acc[mt][nt][v];
  } else if (role == 1) {
    f16* FT = FTcur + (size_t)b * 16384;
#pragma unroll
    for (int mt = 0; mt < 2; ++mt)
#pragma unroll
      for (int nt = 0; nt < 8; ++nt) {
        f16x4 pk;
#pragma unroll
        for (int v = 0; v < 4; ++v) pk[v] = (f16)acc[mt][nt][v];
        *(f16x4*)(FT + (size_t)(nt * 16 + lr) * 128 + w * 32 + mt * 16 + lg * 4) = pk;
      }
  } else {
    // column log-softmax + diag loss, wave-parallel
    __syncthreads();
    float* redm = (float*)sL;          // [128][4]
    float* redM = redm + 512;          // [128]
    float* reds = redM + 128;          // [128][4]
    float* redL = reds + 512;          // [128]
    float* redW = redL + 128;          // [4]
#pragma unroll
    for (int nt = 0; nt < 8; ++nt) {
      float pm = -1e30f;
#pragma unroll
      for (int mt = 0; mt < 2; ++mt)
#pragma unroll
        for (int v = 0; v < 4; ++v) pm = fmaxf(pm, acc[mt][nt][v]);
      pm = fmaxf(pm, __shfl_xor(pm, 16, 64));
      pm = fmaxf(pm, __shfl_xor(pm, 32, 64));
      if (lg == 0) redm[(nt * 16 + lr) * 4 + w] = pm;
    }
    __syncthreads();
    if (t < 128) redM[t] = fmaxf(fmaxf(redm[t * 4], redm[t * 4 + 1]),
                                 fmaxf(redm[t * 4 + 2], redm[t * 4 + 3]));
    __syncthreads();
#pragma unroll
    for (int nt = 0; nt < 8; ++nt) {
      const float mc = redM[nt * 16 + lr];
      float ps = 0.f;
#pragma unroll
      for (int mt = 0; mt < 2; ++mt)
#pragma unroll
        for (int v = 0; v < 4; ++v) ps += expf(acc[mt][nt][v] - mc);
      ps += __shfl_xor(ps, 16, 64);
      ps += __shfl_xor(ps, 32, 64);
      if (lg == 0) reds[(nt * 16 + lr) * 4 + w] = ps;
    }
    __syncthreads();
    if (t < 128) redL[t] = logf(reds[t * 4] + reds[t * 4 + 1] + reds[t * 4 + 2] + reds[t * 4 + 3]);
    __syncthreads();
    float contrib = 0.f;
#pragma unroll
    for (int mt = 0; mt < 2; ++mt)
#pragma unroll
      for (int nt = 0; nt < 8; ++nt)
#pragma unroll
        for (int v = 0; v < 4; ++v) {
          const int r = w * 32 + mt * 16 + lg * 4 + v, c = nt * 16 + lr;
          if (r == c) contrib += acc[mt][nt][v] - redM[c] - redL[c];
        }
#pragma unroll
    for (int off = 1; off < 64; off <<= 1) contrib += __shfl_xor(contrib, off, 64);
    if (lane == 0) redW[w] = contrib;
    __syncthreads();
    if (t == 0) atomicAdd(loss, redW[0] + redW[1] + redW[2] + redW[3]);
  }
}

__global__ void k_final(const float* __restrict__ acc, float* __restrict__ out) {
  out[0] = -acc[0] * (1.f / 131072.f);
}

extern "C" void kernel_launch(void* const* d_in, const int* in_sizes, int n_in,
                              void* d_out, int out_size, void* d_ws, size_t ws_size,
                              hipStream_t stream) {
  const float* seq = (const float*)d_in[0];
  const float* w1  = (const float*)d_in[1];
  const float* b1  = (const float*)d_in[2];
  const float* w2  = (const float*)d_in[3];
  const float* b2  = (const float*)d_in[4];
  const float* lw  = (const float*)d_in[5];
  const float* lb  = (const float*)d_in[6];
  float* out = (float*)d_out;

  // ws layout (f16 units unless noted)
  f16* emb16 = (f16*)d_ws;                 // 10240*128        = 1,310,720
  f16* Srow  = emb16 + 1310720;            // 8*18*16384       = 2,359,296
  f16* ST    = Srow + 2359296;             // 2,359,296
  f16* Pb    = ST + 2359296;               // 2 * 131072
  f16* FTb   = Pb + 262144;                // 2 * 131072
  f16* w2p   = FTb + 262144;               // 36,864
  float* lwT = (float*)(w2p + 36864);      // 8192 f32
  float* lossAcc = lwT + 8192;             // 1 f32

  float* Aout = out + 1;

  k_repack<<<72, 256, 0, stream>>>(w2, lw, w2p, lwT, lossAcc);
  k_encoder<<<10240, 256, 0, stream>>>(seq, w1, b1, w2p, b2, lwT, lb, emb16);
  k_affinity<<<72, 256, 0, stream>>>(emb16, Aout);
  k_softmax<<<72, 128, 0, stream>>>(Aout, Srow, ST, lossAcc);
  for (int k = 2; k <= 9; ++k) {
    const int cur = k & 1, prev = cur ^ 1;
    k_chain<<<24, 256, 0, stream>>>(k, Srow, ST,
        Pb + cur * 131072, Pb + prev * 131072,
        FTb + cur * 131072, FTb + prev * 131072,
        lossAcc);
  }
  k_final<<<1, 1, 0, stream>>>(lossAcc, out);
}

// Round 6
// 276.511 us; speedup vs baseline: 5.4311x; 1.0635x over previous
//
#include <hip/hip_runtime.h>
#include <math.h>

typedef _Float16 f16;
typedef f16 f16x8 __attribute__((ext_vector_type(8)));
typedef f16 f16x4 __attribute__((ext_vector_type(4)));
typedef float f32x4 __attribute__((ext_vector_type(4)));

// ---- repack: w2 -> f16 hi/lo [h/l][tap][oc][ic]; w1 -> w1p[oc][k32] (hi k=0..8, lo k=16..24); lw -> lwT
__global__ __launch_bounds__(256) void k_repack(const float* __restrict__ w2,
                                                const float* __restrict__ w1,
                                                const float* __restrict__ lw,
                                                f16* __restrict__ w2p,
                                                f16* __restrict__ w1p,
                                                float* __restrict__ lwT,
                                                float* __restrict__ lossAcc) {
  const int i = blockIdx.x * 256 + threadIdx.x;
  if (i == 0) lossAcc[0] = 0.f;
  if (i < 18432) {
    const int ic = i & 31, oc = (i >> 5) & 63, tap = i >> 11;
    const float w = w2[oc * 288 + ic * 9 + tap];
    const f16 wh = (f16)w;
    w2p[i] = wh;
    w2p[18432 + i] = (f16)(w - (float)wh);
  }
  if (i < 1024) {
    const int oc = i >> 5, k = i & 31;
    f16 r = (f16)0.f;
    if (k < 9) r = (f16)w1[oc * 9 + k];
    else if (k >= 16 && k < 25) {
      const float w = w1[oc * 9 + (k - 16)];
      r = (f16)(w - (float)((f16)w));
    }
    w1p[i] = r;
  }
  if (i < 8192) lwT[i] = lw[(i & 63) * 128 + (i >> 6)];  // lwT[o][c]
}

// ---- fused encoder: conv1 (MFMA, hi/lo packed K=32) -> conv2 (MFMA hi+lo) -> pool -> linear -> L2norm
__global__ __launch_bounds__(256, 4) void k_encoder(
    const float* __restrict__ seq,
    const f16* __restrict__ w1p, const float* __restrict__ b1,
    const f16* __restrict__ w2p, const float* __restrict__ b2,
    const float* __restrict__ lwT, const float* __restrict__ lb,
    f16* __restrict__ emb16)
{
  __shared__ float s_in[33 * 33];
  __shared__ __align__(16) f16 s_h1[289 * 40];  // row = iy*17+ix, 80B stride; pad rows zeroed
  __shared__ __align__(16) float s_pool[64];
  __shared__ float s_part[2];
  const int t = threadIdx.x, lane = t & 63, wv = t >> 6;
  const int lr = lane & 15, lg = lane >> 4;

  const float* x = seq + (size_t)blockIdx.x * 1024;
  for (int i = t; i < 1024; i += 256)
    s_in[(i >> 5) * 33 + (i & 31)] = x[i];
  if (t < 33) s_in[32 * 33 + t] = 0.f;
  if (t < 32) s_in[t * 33 + 32] = 0.f;
  if (t < 132) {
    const int zi = t >> 2, ch = t & 3;
    const int row = (zi < 16) ? zi * 17 + 16 : 272 + (zi - 16);
    *(f32x4*)&s_h1[row * 40 + ch * 8] = f32x4{0.f, 0.f, 0.f, 0.f};
  }
  // conv1 B fragments + biases
  f16x8 w1f[2];
  float b1v[2];
#pragma unroll
  for (int n = 0; n < 2; ++n) {
    w1f[n] = *(const f16x8*)(w1p + (n * 16 + lr) * 32 + lg * 8);
    b1v[n] = b1[n * 16 + lr];
  }
  __syncthreads();

  // conv1 via mfma_f32_16x16x32_f16: m-tile = output row oy, M=16 ox, N=2x16 oc, K=32 (hi|lo taps)
  {
    const bool odd = lg & 1;
    f32x4 a1[4][2];
#pragma unroll
    for (int m = 0; m < 4; ++m) {
      const int oy = wv * 4 + m;
      const int base = 66 * oy + 2 * lr;
      f16x8 af;
      af[0] = (f16)s_in[base + (odd ? 68 : 0)];
      { const float v = s_in[base + 1];  af[1] = odd ? (f16)0.f : (f16)v; }
      { const float v = s_in[base + 2];  af[2] = odd ? (f16)0.f : (f16)v; }
      { const float v = s_in[base + 33]; af[3] = odd ? (f16)0.f : (f16)v; }
      { const float v = s_in[base + 34]; af[4] = odd ? (f16)0.f : (f16)v; }
      { const float v = s_in[base + 35]; af[5] = odd ? (f16)0.f : (f16)v; }
      { const float v = s_in[base + 66]; af[6] = odd ? (f16)0.f : (f16)v; }
      { const float v = s_in[base + 67]; af[7] = odd ? (f16)0.f : (f16)v; }
#pragma unroll
      for (int n = 0; n < 2; ++n) {
        const f32x4 c0 = f32x4{b1v[n], b1v[n], b1v[n], b1v[n]};
        a1[m][n] = __builtin_amdgcn_mfma_f32_16x16x32_f16(af, w1f[n], c0, 0, 0, 0);
      }
    }
#pragma unroll
    for (int m = 0; m < 4; ++m) {
      const int oy = wv * 4 + m;
#pragma unroll
      for (int n = 0; n < 2; ++n)
#pragma unroll
        for (int v = 0; v < 4; ++v)
          s_h1[(oy * 17 + lg * 4 + v) * 40 + n * 16 + lr] = (f16)fmaxf(a1[m][n][v], 0.f);
    }
  }
  // conv2 B-fragments (hi/lo)
  f16x8 bh[9], bl[9];
  float bias2;
  {
    const int oc = wv * 16 + lr;
#pragma unroll
    for (int tap = 0; tap < 9; ++tap) {
      bh[tap] = *(const f16x8*)(w2p + ((tap * 64 + oc) * 32 + lg * 8));
      bl[tap] = *(const f16x8*)(w2p + 18432 + ((tap * 64 + oc) * 32 + lg * 8));
    }
    bias2 = b2[oc];
  }
  __syncthreads();

  // conv2 MFMA: M=64 pos (4 tiles), N=16 oc (this wave), K=32 ic per tap
  {
    f32x4 acc[4];
#pragma unroll
    for (int m = 0; m < 4; ++m) acc[m] = f32x4{bias2, bias2, bias2, bias2};
#pragma unroll
    for (int m = 0; m < 4; ++m) {
      const int opos = m * 16 + lr, oy = opos >> 3, ox = opos & 7;
      const int baddr = (34 * oy + 2 * ox) * 40 + lg * 8;
#pragma unroll
      for (int dy = 0; dy < 3; ++dy)
#pragma unroll
        for (int dx = 0; dx < 3; ++dx) {
          const int tap = dy * 3 + dx;
          const f16x8 afr = *(const f16x8*)&s_h1[baddr + (dy * 17 + dx) * 40];
          acc[m] = __builtin_amdgcn_mfma_f32_16x16x32_f16(afr, bh[tap], acc[m], 0, 0, 0);
          acc[m] = __builtin_amdgcn_mfma_f32_16x16x32_f16(afr, bl[tap], acc[m], 0, 0, 0);
        }
    }
    float s = 0.f;
#pragma unroll
    for (int m = 0; m < 4; ++m)
#pragma unroll
      for (int v = 0; v < 4; ++v) s += fmaxf(acc[m][v], 0.f);
    s += __shfl_xor(s, 16, 64);
    s += __shfl_xor(s, 32, 64);
    if (lane < 16) s_pool[wv * 16 + lane] = s * (1.f / 64.f);
  }
  __syncthreads();
  // linear 64->128 + L2 normalize, f16 out
  float val = 0.f;
  if (t < 128) {
    val = lb[t];
    const float* lrow = lwT + t * 64;
#pragma unroll
    for (int c4 = 0; c4 < 16; ++c4) {
      const f32x4 wv4 = *(const f32x4*)(lrow + c4 * 4);
      const f32x4 pv = *(const f32x4*)&s_pool[c4 * 4];
      val = fmaf(pv[0], wv4[0], val);
      val = fmaf(pv[1], wv4[1], val);
      val = fmaf(pv[2], wv4[2], val);
      val = fmaf(pv[3], wv4[3], val);
    }
  }
  float sq = val * val;
#pragma unroll
  for (int off = 1; off < 64; off <<= 1) sq += __shfl_xor(sq, off, 64);
  if (t < 128 && (t & 63) == 0) s_part[t >> 6] = sq;
  __syncthreads();
  if (t < 128) {
    const float nrm = sqrtf(s_part[0] + s_part[1]);
    emb16[(size_t)blockIdx.x * 128 + t] = (f16)(val / fmaxf(nrm, 1e-12f));
  }
}

// ---- fused affinity + dual softmax (+ At_1 loss at tt==0)
// Stores only the layouts the chain reads: Srow j in {2..7,17}; ST j in {1,10..16}.
__global__ __launch_bounds__(256) void k_affsm(
    const f16* __restrict__ emb16, float* __restrict__ Aout,
    f16* __restrict__ Srow, f16* __restrict__ ST, float* __restrict__ loss)
{
  __shared__ __align__(16) f16 sL[16384];
  __shared__ __align__(16) f16 sR[16384];
  __shared__ __align__(16) f16 sT[128 * 136];
  __shared__ float s_cm[128], s_cd[128];
  __shared__ float s_red4[512];
  __shared__ float s_lred[4];
  const int bid = blockIdx.x, b = bid / 9, tt = bid % 9;
  const int t = threadIdx.x, lane = t & 63, w = t >> 6;
  const int lr = lane & 15, lg = lane >> 4;
  const f16* Ea = emb16 + (size_t)(b * 10 + tt) * 16384;
  const f16* Eb = Ea + 16384;
#pragma unroll
  for (int j = 0; j < 8; ++j) {
    const int ck = j * 256 + t, row = ck >> 4, c16 = ck & 15;
    const int off = ((row << 8) + (c16 << 4)) ^ ((row & 7) << 4);
    *(f16x8*)((char*)sL + off) = *(const f16x8*)(Ea + ck * 8);
    *(f16x8*)((char*)sR + off) = *(const f16x8*)(Eb + ck * 8);
  }
  __syncthreads();
  f32x4 acc[2][8] = {};
#pragma unroll
  for (int kt = 0; kt < 4; ++kt) {
    int row = w * 32 + lr;
    int byt = ((row << 8) + kt * 64 + (lg << 4)) ^ ((row & 7) << 4);
    const f16x8 a0 = *(const f16x8*)((char*)sL + byt);
    row += 16;
    byt = ((row << 8) + kt * 64 + (lg << 4)) ^ ((row & 7) << 4);
    const f16x8 a1 = *(const f16x8*)((char*)sL + byt);
#pragma unroll
    for (int nt = 0; nt < 8; ++nt) {
      const int rb = nt * 16 + lr;
      const int bb = ((rb << 8) + kt * 64 + (lg << 4)) ^ ((rb & 7) << 4);
      const f16x8 bv = *(const f16x8*)((char*)sR + bb);
      acc[0][nt] = __builtin_amdgcn_mfma_f32_16x16x32_f16(a0, bv, acc[0][nt], 0, 0, 0);
      acc[1][nt] = __builtin_amdgcn_mfma_f32_16x16x32_f16(a1, bv, acc[1][nt], 0, 0, 0);
    }
  }
#pragma unroll
  for (int mt = 0; mt < 2; ++mt)
#pragma unroll
    for (int nt = 0; nt < 8; ++nt)
#pragma unroll
      for (int v = 0; v < 4; ++v) acc[mt][nt][v] *= (1.f / 0.07f);

  // write A
  float* Og = Aout + (size_t)bid * 16384;
#pragma unroll
  for (int mt = 0; mt < 2; ++mt)
#pragma unroll
    for (int nt = 0; nt < 8; ++nt)
#pragma unroll
      for (int v = 0; v < 4; ++v)
        Og[(w * 32 + mt * 16 + lg * 4 + v) * 128 + nt * 16 + lr] = acc[mt][nt][v];

  // row stats (rows lane-local across lr bits)
  float rm[2][4], rd[2][4];
#pragma unroll
  for (int mt = 0; mt < 2; ++mt)
#pragma unroll
    for (int v = 0; v < 4; ++v) {
      float m = -1e30f;
#pragma unroll
      for (int nt = 0; nt < 8; ++nt) m = fmaxf(m, acc[mt][nt][v]);
      m = fmaxf(m, __shfl_xor(m, 1, 64));
      m = fmaxf(m, __shfl_xor(m, 2, 64));
      m = fmaxf(m, __shfl_xor(m, 4, 64));
      m = fmaxf(m, __shfl_xor(m, 8, 64));
      float s = 0.f;
#pragma unroll
      for (int nt = 0; nt < 8; ++nt) s += expf(acc[mt][nt][v] - m);
      s += __shfl_xor(s, 1, 64);
      s += __shfl_xor(s, 2, 64);
      s += __shfl_xor(s, 4, 64);
      s += __shfl_xor(s, 8, 64);
      rm[mt][v] = m;
      rd[mt][v] = 1.f / s;
    }
  // col stats
#pragma unroll
  for (int nt = 0; nt < 8; ++nt) {
    float m = -1e30f;
#pragma unroll
    for (int mt = 0; mt < 2; ++mt)
#pragma unroll
      for (int v = 0; v < 4; ++v) m = fmaxf(m, acc[mt][nt][v]);
    m = fmaxf(m, __shfl_xor(m, 16, 64));
    m = fmaxf(m, __shfl_xor(m, 32, 64));
    if (lg == 0) s_red4[(nt * 16 + lr) * 4 + w] = m;
  }
  __syncthreads();
  if (t < 128) s_cm[t] = fmaxf(fmaxf(s_red4[t * 4], s_red4[t * 4 + 1]),
                               fmaxf(s_red4[t * 4 + 2], s_red4[t * 4 + 3]));
  __syncthreads();
#pragma unroll
  for (int nt = 0; nt < 8; ++nt) {
    const float mc = s_cm[nt * 16 + lr];
    float s = 0.f;
#pragma unroll
    for (int mt = 0; mt < 2; ++mt)
#pragma unroll
      for (int v = 0; v < 4; ++v) s += expf(acc[mt][nt][v] - mc);
    s += __shfl_xor(s, 16, 64);
    s += __shfl_xor(s, 32, 64);
    if (lg == 0) s_red4[(nt * 16 + lr) * 4 + w] = s;
  }
  __syncthreads();
  if (t < 128) s_cd[t] = 1.f / (s_red4[t * 4] + s_red4[t * 4 + 1] +
                                s_red4[t * 4 + 2] + s_red4[t * 4 + 3]);
  __syncthreads();

  const bool wantSfD = (tt >= 2 && tt <= 7);
  const bool wantSfT = (tt == 1);
  const bool wantSbD = (tt >= 1 && tt <= 7);
  const bool wantSbT = (tt == 0);
  f16* SfD = Srow + (size_t)(b * 18 + tt) * 16384;
  f16* SbD = ST + (size_t)(b * 18 + 17 - tt) * 16384;

  float contrib = 0.f;
#pragma unroll
  for (int mt = 0; mt < 2; ++mt)
#pragma unroll
    for (int v = 0; v < 4; ++v) {
      const int r = w * 32 + mt * 16 + lg * 4 + v;
      float qsum = 0.f, dval = 0.f;
#pragma unroll
      for (int nt = 0; nt < 8; ++nt) {
        const int c = nt * 16 + lr;
        const float a = acc[mt][nt][v];
        const float sf = expf(a - rm[mt][v]) * rd[mt][v];
        const float sb = expf(a - s_cm[c]) * s_cd[c];
        if (wantSfD) SfD[r * 128 + c] = (f16)sf;
        if (wantSbD) SbD[r * 128 + c] = (f16)sb;
        if (wantSfT) sT[c * 136 + r] = (f16)sf;
        if (wantSbT) {
          sT[c * 136 + r] = (f16)sb;
          qsum += expf(sb);
          if (nt == (w * 2 + mt)) dval = sb;
        }
      }
      if (wantSbT) {
        qsum += __shfl_xor(qsum, 1, 64);
        qsum += __shfl_xor(qsum, 2, 64);
        qsum += __shfl_xor(qsum, 4, 64);
        qsum += __shfl_xor(qsum, 8, 64);
        if (lr == lg * 4 + v) contrib += dval - logf(qsum);
      }
    }
  if (wantSfT || wantSbT) {
    __syncthreads();
    f16* dst = wantSfT ? (ST + (size_t)(b * 18 + 1) * 16384)
                       : (Srow + (size_t)(b * 18 + 17) * 16384);
#pragma unroll
    for (int j = 0; j < 8; ++j) {
      const int e = (j * 256 + t) * 8;
      *(f16x8*)(dst + e) = *(const f16x8*)&sT[(e >> 7) * 136 + (e & 127)];
    }
  }
  if (wantSbT) {
#pragma unroll
    for (int off = 1; off < 64; off <<= 1) contrib += __shfl_xor(contrib, off, 64);
    if (lane == 0) s_lred[w] = contrib;
    __syncthreads();
    if (t == 0) atomicAdd(loss, s_lred[0] + s_lred[1] + s_lred[2] + s_lred[3]);
  }
}

// ---- chain step (per-k launch, proven structure): roles P / F^T / loss
__global__ __launch_bounds__(256) void k_chain(
    int k,
    const f16* __restrict__ Srow, const f16* __restrict__ ST,
    f16* __restrict__ Pcur, const f16* __restrict__ Pprev,
    f16* __restrict__ FTcur, const f16* __restrict__ FTprev,
    float* __restrict__ loss)
{
  __shared__ __align__(16) f16 sL[16384];
  __shared__ __align__(16) f16 sRt[16384];
  const int role = blockIdx.x >> 3, b = blockIdx.x & 7;
  const int t = threadIdx.x, lane = t & 63, w = t >> 6;
  const int lr = lane & 15, lg = lane >> 4;

  const f16 *L, *Rt;
  if (role == 0) {
    if (k > 8) return;
    L = (k == 2) ? (Srow + (size_t)(b * 18 + 17) * 16384) : (Pprev + (size_t)b * 16384);
    Rt = ST + (size_t)(b * 18 + (18 - k)) * 16384;
  } else if (role == 1) {
    if (k < 3 || k > 8) return;
    L = Srow + (size_t)(b * 18 + (k - 1)) * 16384;
    Rt = (k == 3) ? (ST + (size_t)(b * 18 + 1) * 16384) : (FTprev + (size_t)b * 16384);
  } else {
    if (k < 3) return;
    L = Pprev + (size_t)b * 16384;
    Rt = (k == 3) ? (ST + (size_t)(b * 18 + 1) * 16384) : (FTprev + (size_t)b * 16384);
  }
#pragma unroll
  for (int j = 0; j < 8; ++j) {
    const int ck = j * 256 + t, row = ck >> 4, c16 = ck & 15;
    const int off = ((row << 8) + (c16 << 4)) ^ ((row & 7) << 4);
    *(f16x8*)((char*)sL + off) = *(const f16x8*)(L + ck * 8);
    *(f16x8*)((char*)sRt + off) = *(const f16x8*)(Rt + ck * 8);
  }
  __syncthreads();
  f32x4 acc[2][8] = {};
#pragma unroll
  for (int kt = 0; kt < 4; ++kt) {
    int row = w * 32 + lr;
    int byt = ((row << 8) + kt * 64 + (lg << 4)) ^ ((row & 7) << 4);
    const f16x8 a0 = *(const f16x8*)((char*)sL + byt);
    row += 16;
    byt = ((row << 8) + kt * 64 + (lg << 4)) ^ ((row & 7) << 4);
    const f16x8 a1 = *(const f16x8*)((char*)sL + byt);
#pragma unroll
    for (int nt = 0; nt < 8; ++nt) {
      const int rb = nt * 16 + lr;
      const int bb = ((rb << 8) + kt * 64 + (lg << 4)) ^ ((rb & 7) << 4);
      const f16x8 bv = *(const f16x8*)((char*)sRt + bb);
      acc[0][nt] = __builtin_amdgcn_mfma_f32_16x16x32_f16(a0, bv, acc[0][nt], 0, 0, 0);
      acc[1][nt] = __builtin_amdgcn_mfma_f32_16x16x32_f16(a1, bv, acc[1][nt], 0, 0, 0);
    }
  }
  if (role == 0) {
    f16* P = Pcur + (size_t)b * 16384;
#pragma unroll
    for (int mt = 0; mt < 2; ++mt)
#pragma unroll
      for (int nt = 0; nt < 8; ++nt)
#pragma unroll
        for (int v = 0; v < 4; ++v)
          P[(w * 32 + mt * 16 + lg * 4 + v) * 128 + nt * 16 + lr] = (f16)acc[mt][nt][v];
  } else if (role == 1) {
    f16* FT = FTcur + (size_t)b * 16384;
#pragma unroll
    for (int mt = 0; mt < 2; ++mt)
#pragma unroll
      for (int nt = 0; nt < 8; ++nt) {
        f16x4 pk;
#pragma unroll
        for (int v = 0; v < 4; ++v) pk[v] = (f16)acc[mt][nt][v];
        *(f16x4*)(FT + (size_t)(nt * 16 + lr) * 128 + w * 32 + mt * 16 + lg * 4) = pk;
      }
  } else {
    // column log-softmax + diag loss, wave-parallel
    __syncthreads();
    float* redm = (float*)sL;          // [128][4]
    float* redM = redm + 512;          // [128]
    float* reds = redM + 128;          // [128][4]
    float* redL = reds + 512;          // [128]
    float* redW = redL + 128;          // [4]
#pragma unroll
    for (int nt = 0; nt < 8; ++nt) {
      float pm = -1e30f;
#pragma unroll
      for (int mt = 0; mt < 2; ++mt)
#pragma unroll
        for (int v = 0; v < 4; ++v) pm = fmaxf(pm, acc[mt][nt][v]);
      pm = fmaxf(pm, __shfl_xor(pm, 16, 64));
      pm = fmaxf(pm, __shfl_xor(pm, 32, 64));
      if (lg == 0) redm[(nt * 16 + lr) * 4 + w] = pm;
    }
    __syncthreads();
    if (t < 128) redM[t] = fmaxf(fmaxf(redm[t * 4], redm[t * 4 + 1]),
                                 fmaxf(redm[t * 4 + 2], redm[t * 4 + 3]));
    __syncthreads();
#pragma unroll
    for (int nt = 0; nt < 8; ++nt) {
      const float mc = redM[nt * 16 + lr];
      float ps = 0.f;
#pragma unroll
      for (int mt = 0; mt < 2; ++mt)
#pragma unroll
        for (int v = 0; v < 4; ++v) ps += expf(acc[mt][nt][v] - mc);
      ps += __shfl_xor(ps, 16, 64);
      ps += __shfl_xor(ps, 32, 64);
      if (lg == 0) reds[(nt * 16 + lr) * 4 + w] = ps;
    }
    __syncthreads();
    if (t < 128) redL[t] = logf(reds[t * 4] + reds[t * 4 + 1] +
                                reds[t * 4 + 2] + reds[t * 4 + 3]);
    __syncthreads();
    float contrib = 0.f;
#pragma unroll
    for (int mt = 0; mt < 2; ++mt)
#pragma unroll
      for (int nt = 0; nt < 8; ++nt)
#pragma unroll
        for (int v = 0; v < 4; ++v) {
          const int r = w * 32 + mt * 16 + lg * 4 + v, c = nt * 16 + lr;
          if (r == c) contrib += acc[mt][nt][v] - redM[c] - redL[c];
        }
#pragma unroll
    for (int off = 1; off < 64; off <<= 1) contrib += __shfl_xor(contrib, off, 64);
    if (lane == 0) redW[w] = contrib;
    __syncthreads();
    if (t == 0) atomicAdd(loss, redW[0] + redW[1] + redW[2] + redW[3]);
  }
}

__global__ void k_final(const float* __restrict__ acc, float* __restrict__ out) {
  out[0] = -acc[0] * (1.f / 131072.f);
}

extern "C" void kernel_launch(void* const* d_in, const int* in_sizes, int n_in,
                              void* d_out, int out_size, void* d_ws, size_t ws_size,
                              hipStream_t stream) {
  const float* seq = (const float*)d_in[0];
  const float* w1  = (const float*)d_in[1];
  const float* b1  = (const float*)d_in[2];
  const float* w2  = (const float*)d_in[3];
  const float* b2  = (const float*)d_in[4];
  const float* lw  = (const float*)d_in[5];
  const float* lb  = (const float*)d_in[6];
  float* out = (float*)d_out;

  f16* emb16 = (f16*)d_ws;                 // 1,310,720
  f16* Srow  = emb16 + 1310720;            // 2,359,296
  f16* ST    = Srow + 2359296;             // 2,359,296
  f16* Pb    = ST + 2359296;               // 262,144
  f16* FTb   = Pb + 262144;                // 262,144
  f16* w2p   = FTb + 262144;               // 36,864
  f16* w1p   = w2p + 36864;                // 1,024
  float* lwT = (float*)(w1p + 1024);       // 8,192 f32
  float* lossAcc = lwT + 8192;             // 1 f32

  float* Aout = out + 1;

  k_repack<<<72, 256, 0, stream>>>(w2, w1, lw, w2p, w1p, lwT, lossAcc);
  k_encoder<<<10240, 256, 0, stream>>>(seq, w1p, b1, w2p, b2, lwT, lb, emb16);
  k_affsm<<<72, 256, 0, stream>>>(emb16, Aout, Srow, ST, lossAcc);
  for (int k = 2; k <= 9; ++k) {
    const int cur = k & 1, prev = cur ^ 1;
    k_chain<<<24, 256, 0, stream>>>(k, Srow, ST,
        Pb + cur * 131072, Pb + prev * 131072,
        FTb + cur * 131072, FTb + prev * 131072,
        lossAcc);
  }
  k_final<<<1, 1, 0, stream>>>(lossAcc, out);
}